// Round 4
// baseline (41.418 us; speedup 1.0000x reference)
//
#include <hip/hip_runtime.h>
#include <hip/hip_bf16.h>

// Encoder: B=16, n=1024, C=256, K=32, fp32 in/out.
// GEMM1 (MFMA): dot[n,k] = x.cw^T ; sqnorm = xx - 2 dot + cc (fp32 softmax args)
// w = softmax_k(sf*sqnorm)
// GEMM2 (MFMA): S1[k,c] = sum_n w[n,k] x[n,c]  (bf16 in, fp32 accum)
// enc = S1 - wsum*cw;  out[b,c] = sum_k relu((enc-mean)*rsqrt(var+eps)*gamma+beta)
//
// XCD-affinity: producer blocks for batch b satisfy bid%8 == b%8, so all
// partials for a batch live in ONE XCD's L2 (2.1 MB < 4 MB); the reducer
// decodes the same map -> same-XCD L2 hits instead of cross-XCD HBM refetch.

#define BN_EPS 1e-3f

typedef __attribute__((ext_vector_type(8))) short short8;
typedef __attribute__((ext_vector_type(4))) float f32x4;

static __device__ inline unsigned short f2bf(float f) {
    unsigned int u = __float_as_uint(f);
    unsigned int r = (u + 0x7fffu + ((u >> 16) & 1u)) >> 16;
    return (unsigned short)r;
}

static __device__ inline short8 pack8(float4 u, float4 v) {
    short8 r;
    r[0] = (short)f2bf(u.x); r[1] = (short)f2bf(u.y);
    r[2] = (short)f2bf(u.z); r[3] = (short)f2bf(u.w);
    r[4] = (short)f2bf(v.x); r[5] = (short)f2bf(v.y);
    r[6] = (short)f2bf(v.z); r[7] = (short)f2bf(v.w);
    return r;
}

#if __has_builtin(__builtin_amdgcn_global_load_lds)
#define HAVE_GLOAD_LDS 1
typedef const __attribute__((address_space(1))) void* as1_cvp;
typedef __attribute__((address_space(3))) void* as3_vp;
static __device__ inline void gload_lds16(const void* g, void* s) {
    __builtin_amdgcn_global_load_lds((as1_cvp)g, (as3_vp)s, 16, 0, 0);
}
#else
#define HAVE_GLOAD_LDS 0
#endif

// producer block id for (batch b, tile jj):  bid%8==b%8, all tiles of b on one XCD
static __device__ __host__ inline int pbid(int b, int jj) {
    return (b & 7) | ((((b >> 3) << 5) + jj) << 3);
}

// ---------------- MFMA main kernel: 512 blocks, 256 thr ----------------------
__global__ __launch_bounds__(256, 2) void enc_main_mfma(
    const float* __restrict__ x, const float* __restrict__ cw,
    const float* __restrict__ sf, float* __restrict__ pS1, float* __restrict__ pW)
{
    const int bid = blockIdx.x;
    const int m_  = bid >> 3;
    const int b   = (bid & 7) + 8 * (m_ >> 5);   // batch (XCD-affine)
    const int jb  = m_ & 31;                     // position tile within batch
    const int t = threadIdx.x;
    const int w = t >> 6;
    const int lane = t & 63;

    __shared__ float4 xs4[32][65];           // x tile fp32, row = 65 float4 (1040B)
    __shared__ unsigned short xbf[32][272];  // x tile bf16 (row 544B, 16B aligned)
    __shared__ unsigned short wT[32][40];    // w^T bf16 [k][n], row 80B
    __shared__ float4 dred[2][2][2][64];     // [Mtile][chHalf][Ntile][lane]
    __shared__ float  xxr[2][2][16];
    __shared__ float  ccred[8][32];
    __shared__ float  cc_lds[32];
    __shared__ float  sf_lds[32];
    __shared__ float  w_lds[32][33];         // fp32 w [pos][k] (for wsum)

    // ---- phase 0: stage x (async DMA), cc partials, sf ----
    const int nbase = jb * 32;
    const float4* gx4 = (const float4*)(x + (size_t)b * 1024 * 256) + (size_t)nbase * 64;
#if HAVE_GLOAD_LDS
    #pragma unroll
    for (int i = 0; i < 8; ++i) {
        const int row = w * 8 + i;
        gload_lds16(gx4 + row * 64 + lane, &xs4[row][0]);
    }
#else
    {
        const int p = t >> 3, q = t & 7;
        #pragma unroll
        for (int j = 0; j < 8; ++j)
            xs4[p][q + 8 * j] = gx4[p * 64 + q + 8 * j];
    }
#endif
    {
        const int k = t >> 3, seg = t & 7;   // thread covers cw[k][seg*32 .. +31]
        const float4* cw4 = (const float4*)cw;
        float s = 0.f;
        #pragma unroll
        for (int j = 0; j < 8; ++j) {
            float4 cv = cw4[k * 64 + seg * 8 + j];
            s += cv.x * cv.x + cv.y * cv.y + cv.z * cv.z + cv.w * cv.w;
        }
        ccred[seg][k] = s;
    }
    if (t < 32) sf_lds[t] = sf[t];
    __syncthreads();

    // ---- phase 1: GEMM1 dot = x.cw^T ; also materialize xbf ----
    const int mt = w >> 1, half = w & 1;
    const int lrow = lane & 15;
    const int lk8 = (lane >> 4) * 8;
    const float* xsf = (const float*)xs4;

    {
        f32x4 D0 = {0.f, 0.f, 0.f, 0.f}, D1 = {0.f, 0.f, 0.f, 0.f};
        float xxp = 0.f;
        #pragma unroll
        for (int ks = 0; ks < 4; ++ks) {
            const int ch = half * 128 + ks * 32 + lk8;
            const int row = mt * 16 + lrow;
            const float* ap = xsf + row * 260 + ch;
            float4 u = *(const float4*)ap;
            float4 v = *(const float4*)(ap + 4);
            xxp += u.x * u.x + u.y * u.y + u.z * u.z + u.w * u.w
                 + v.x * v.x + v.y * v.y + v.z * v.z + v.w * v.w;
            short8 a = pack8(u, v);
            *(short8*)&xbf[row][ch] = a;     // bf16 x for GEMM2 (quadrant-owned)
            const float* b0p = cw + lrow * 256 + ch;
            const float* b1p = cw + (16 + lrow) * 256 + ch;
            short8 b0 = pack8(*(const float4*)b0p, *(const float4*)(b0p + 4));
            short8 b1 = pack8(*(const float4*)b1p, *(const float4*)(b1p + 4));
            D0 = __builtin_amdgcn_mfma_f32_16x16x32_bf16(a, b0, D0, 0, 0, 0);
            D1 = __builtin_amdgcn_mfma_f32_16x16x32_bf16(a, b1, D1, 0, 0, 0);
        }
        xxp += __shfl_xor(xxp, 16, 64);
        xxp += __shfl_xor(xxp, 32, 64);
        if (lane < 16) xxr[mt][half][lane] = xxp;
        dred[mt][half][0][lane] = make_float4(D0[0], D0[1], D0[2], D0[3]);
        dred[mt][half][1][lane] = make_float4(D1[0], D1[1], D1[2], D1[3]);
    }
    if (t < 32) {
        float s = 0.f;
        #pragma unroll
        for (int j = 0; j < 8; ++j) s += ccred[j][t];
        cc_lds[t] = s;
    }
    __syncthreads();

    // ---- phase 2: softmax over k; write w_lds fp32 + wT bf16 ----
    {
        float4 a0 = dred[mt][0][0][lane], b0 = dred[mt][1][0][lane];
        float4 a1 = dred[mt][0][1][lane], b1 = dred[mt][1][1][lane];
        float d0[4] = {a0.x + b0.x, a0.y + b0.y, a0.z + b0.z, a0.w + b0.w};
        float d1[4] = {a1.x + b1.x, a1.y + b1.y, a1.z + b1.z, a1.w + b1.w};
        const int k0 = lane & 15, k1 = 16 + k0;
        const float sf0 = sf_lds[k0], sf1 = sf_lds[k1];
        const float cc0 = cc_lds[k0], cc1 = cc_lds[k1];
        #pragma unroll
        for (int r = 0; r < 4; ++r) {
            const int pl = (lane >> 4) * 4 + r;
            const float xxv = xxr[mt][0][pl] + xxr[mt][1][pl];
            float s0 = sf0 * (xxv - 2.f * d0[r] + cc0);
            float s1 = sf1 * (xxv - 2.f * d1[r] + cc1);
            float m = fmaxf(s0, s1);
            #pragma unroll
            for (int msk = 1; msk <= 8; msk <<= 1) m = fmaxf(m, __shfl_xor(m, msk, 64));
            float e0 = __expf(s0 - m), e1 = __expf(s1 - m);
            float sm = e0 + e1;
            #pragma unroll
            for (int msk = 1; msk <= 8; msk <<= 1) sm += __shfl_xor(sm, msk, 64);
            const float inv = 1.f / sm;
            if (half == 0) {
                const int n = mt * 16 + pl;
                const float w0 = e0 * inv, w1 = e1 * inv;
                w_lds[n][k0] = w0;
                w_lds[n][k1] = w1;
                wT[k0][n] = f2bf(w0);
                wT[k1][n] = f2bf(w1);
            }
        }
    }
    __syncthreads();

    // ---- phase 3: GEMM2 S1 = w^T . x ; write pS1 + pW ----
    {
        const int g = lane >> 4;
        short8 a0 = *(const short8*)&wT[lrow][8 * g];
        short8 a1 = *(const short8*)&wT[16 + lrow][8 * g];
        f32x4 E00 = {0,0,0,0}, E01 = {0,0,0,0}, E02 = {0,0,0,0}, E03 = {0,0,0,0};
        f32x4 E10 = {0,0,0,0}, E11 = {0,0,0,0}, E12 = {0,0,0,0}, E13 = {0,0,0,0};
        const int cbase = w * 64;
        const unsigned short* xbu = &xbf[0][0];
        #pragma unroll
        for (int nt = 0; nt < 4; ++nt) {
            const int c = cbase + nt * 16 + lrow;
            short8 bf;
            #pragma unroll
            for (int e = 0; e < 8; ++e)
                bf[e] = (short)xbu[(8 * g + e) * 272 + c];
            if (nt == 0) { E00 = __builtin_amdgcn_mfma_f32_16x16x32_bf16(a0, bf, E00, 0,0,0);
                           E10 = __builtin_amdgcn_mfma_f32_16x16x32_bf16(a1, bf, E10, 0,0,0); }
            if (nt == 1) { E01 = __builtin_amdgcn_mfma_f32_16x16x32_bf16(a0, bf, E01, 0,0,0);
                           E11 = __builtin_amdgcn_mfma_f32_16x16x32_bf16(a1, bf, E11, 0,0,0); }
            if (nt == 2) { E02 = __builtin_amdgcn_mfma_f32_16x16x32_bf16(a0, bf, E02, 0,0,0);
                           E12 = __builtin_amdgcn_mfma_f32_16x16x32_bf16(a1, bf, E12, 0,0,0); }
            if (nt == 3) { E03 = __builtin_amdgcn_mfma_f32_16x16x32_bf16(a0, bf, E03, 0,0,0);
                           E13 = __builtin_amdgcn_mfma_f32_16x16x32_bf16(a1, bf, E13, 0,0,0); }
        }
        float* dst = pS1 + (size_t)bid * 8192;
        const int krow = 4 * g;
        #pragma unroll
        for (int reg = 0; reg < 4; ++reg) {
            const int k0r = (krow + reg) * 256;
            const int k1r = (16 + krow + reg) * 256;
            dst[k0r + cbase +  0 + lrow] = E00[reg];
            dst[k0r + cbase + 16 + lrow] = E01[reg];
            dst[k0r + cbase + 32 + lrow] = E02[reg];
            dst[k0r + cbase + 48 + lrow] = E03[reg];
            dst[k1r + cbase +  0 + lrow] = E10[reg];
            dst[k1r + cbase + 16 + lrow] = E11[reg];
            dst[k1r + cbase + 32 + lrow] = E12[reg];
            dst[k1r + cbase + 48 + lrow] = E13[reg];
        }
    }
    if (t < 32) {
        float s = 0.f;
        #pragma unroll
        for (int p = 0; p < 32; ++p) s += w_lds[p][t];
        pW[bid * 32 + t] = s;
    }
}

// -------- reduce partials -> enc rows + per-block channel stats (64 blocks) --
// block bid: XCD x=bid&7; m=bid>>3 in [0,8): batch b = x + 8*(m>>2), k-group m&3
// handles rows b*32 + [8*kg, 8*kg+8); all pS1/pW producers live on XCD x.
__global__ __launch_bounds__(256) void enc_reduce_stats(
    const float* __restrict__ pS1, const float* __restrict__ pW,
    const float* __restrict__ cw, float* __restrict__ enc, float* __restrict__ pst)
{
    const int bid = blockIdx.x;
    const int xg = bid & 7;
    const int m_ = bid >> 3;
    const int b  = xg + 8 * (m_ >> 2);
    const int kg = m_ & 3;
    const int c = threadIdx.x;

    float s1a = 0.f, s2a = 0.f;
    #pragma unroll
    for (int k8 = 0; k8 < 8; ++k8) {
        const int k = kg * 8 + k8;
        float s = 0.f, ws = 0.f;
        #pragma unroll 8
        for (int jj = 0; jj < 32; ++jj) {
            const int pb = pbid(b, jj);
            s  += pS1[(size_t)pb * 8192 + k * 256 + c];
            ws += pW[pb * 32 + k];
        }
        const float e = s - ws * cw[k * 256 + c];
        enc[(b * 32 + k) * 256 + c] = e;
        s1a += e;
        s2a = fmaf(e, e, s2a);
    }
    pst[bid * 512 + c] = s1a;
    pst[bid * 512 + 256 + c] = s2a;
}

// -------- BN stats finalize + ReLU + sum over k (16 blocks) ------------------
__global__ __launch_bounds__(256) void enc_out(
    const float* __restrict__ enc, const float* __restrict__ pst,
    const float* __restrict__ gamma, const float* __restrict__ beta,
    float* __restrict__ out)
{
    const int b = blockIdx.x;
    const int c = threadIdx.x;
    float S = 0.f, SS = 0.f;
    #pragma unroll 8
    for (int p = 0; p < 64; ++p) {
        S  += pst[p * 512 + c];
        SS += pst[p * 512 + 256 + c];
    }
    const float mean = S * (1.f / 512.f);
    const float var = SS * (1.f / 512.f) - mean * mean;
    const float g = gamma[c] * rsqrtf(var + BN_EPS);
    const float bt = beta[c];
    float o = 0.f;
    #pragma unroll
    for (int k = 0; k < 32; ++k) {
        float e = enc[(b * 32 + k) * 256 + c];
        float v = (e - mean) * g + bt;
        o += fmaxf(v, 0.f);
    }
    out[b * 256 + c] = o;
}

extern "C" void kernel_launch(void* const* d_in, const int* in_sizes, int n_in,
                              void* d_out, int out_size, void* d_ws, size_t ws_size,
                              hipStream_t stream) {
    const float* x     = (const float*)d_in[0];
    const float* cw    = (const float*)d_in[1];
    const float* sf    = (const float*)d_in[2];
    const float* gamma = (const float*)d_in[3];
    const float* beta  = (const float*)d_in[4];
    float* out = (float*)d_out;
    float* ws  = (float*)d_ws;

    float* pS1 = ws;                               // 512*8192
    float* pW  = pS1 + (size_t)512 * 8192;         // 512*32
    float* enc = pW + (size_t)512 * 32;            // 512*256
    float* pst = enc + (size_t)512 * 256;          // 64*512

    enc_main_mfma<<<512, 256, 0, stream>>>(x, cw, sf, pS1, pW);
    enc_reduce_stats<<<64, 256, 0, stream>>>(pS1, pW, cw, enc, pst);
    enc_out<<<16, 256, 0, stream>>>(enc, pst, gamma, beta, out);
}

// Round 5
// 29.039 us; speedup vs baseline: 1.4263x; 1.4263x over previous
//
#include <hip/hip_runtime.h>
#include <hip/hip_bf16.h>

// Encoder: B=16, n=1024, C=256, K=32, fp32 in/out.
// GEMM1 (MFMA): dot[n,k] = x.cw^T ; sqnorm = xx - 2 dot + cc (fp32 softmax args)
// w = softmax_k(sf*sqnorm)
// GEMM2 (MFMA): S1[k,c] = sum_n w[n,k] x[n,c]  (bf16 in, fp32 accum)
// enc = S1 - wsum*cw;  out[b,c] = sum_k relu((enc-mean)*rsqrt(var+eps)*gamma+beta)

#define BN_EPS 1e-3f

typedef __attribute__((ext_vector_type(8))) short short8;
typedef __attribute__((ext_vector_type(4))) float f32x4;

static __device__ inline unsigned short f2bf(float f) {
    unsigned int u = __float_as_uint(f);
    unsigned int r = (u + 0x7fffu + ((u >> 16) & 1u)) >> 16;
    return (unsigned short)r;
}

static __device__ inline short8 pack8(float4 u, float4 v) {
    short8 r;
    r[0] = (short)f2bf(u.x); r[1] = (short)f2bf(u.y);
    r[2] = (short)f2bf(u.z); r[3] = (short)f2bf(u.w);
    r[4] = (short)f2bf(v.x); r[5] = (short)f2bf(v.y);
    r[6] = (short)f2bf(v.z); r[7] = (short)f2bf(v.w);
    return r;
}

#if __has_builtin(__builtin_amdgcn_global_load_lds)
#define HAVE_GLOAD_LDS 1
typedef const __attribute__((address_space(1))) void* as1_cvp;
typedef __attribute__((address_space(3))) void* as3_vp;
static __device__ inline void gload_lds16(const void* g, void* s) {
    __builtin_amdgcn_global_load_lds((as1_cvp)g, (as3_vp)s, 16, 0, 0);
}
#else
#define HAVE_GLOAD_LDS 0
#endif

// phase-0 scratch (cw bf16 + cc partials) overlaid with the GEMM1->softmax
// reduction scratch (dred/xxr): lifetimes are disjoint, separated by a barrier.
union P01 {
    struct {
        unsigned short cwbf[32][264];   // cw bf16, row stride 528B (16B-aligned, 2-way banks)
        float ccred[8][32];
    } p0;
    struct {
        float4 dred[2][2][2][64];       // [Mtile][chHalf][Ntile][lane]
        float  xxr[2][2][16];
    } p1;
};

// ---------------- MFMA main kernel: 512 blocks, 256 thr ----------------------
__global__ __launch_bounds__(256, 2) void enc_main_mfma(
    const float* __restrict__ x, const float* __restrict__ cw,
    const float* __restrict__ sf, float* __restrict__ pS1, float* __restrict__ pW)
{
    const int bid = blockIdx.x;
    const int b   = bid >> 5;                // plain mapping (R4 remap reverted)
    const int jb  = bid & 31;
    const int t = threadIdx.x;
    const int w = t >> 6;
    const int lane = t & 63;

    __shared__ float4 xs4[32][65];           // x tile fp32, row 1040B
    __shared__ unsigned short xbf[32][264];  // x tile bf16, row 528B
    __shared__ P01 u;
    __shared__ unsigned short wT[32][40];    // w^T bf16 [k][n], row 80B
    __shared__ float  cc_lds[32];
    __shared__ float  sf_lds[32];
    __shared__ float  w_lds[32][33];         // fp32 w [pos][k] (for wsum)

    // ---- phase 0: async x->LDS DMA; pack cw->bf16 + cc partials (overlaps) --
    const int nbase = jb * 32;
    const float4* gx4 = (const float4*)(x + (size_t)b * 1024 * 256) + (size_t)nbase * 64;
#if HAVE_GLOAD_LDS
    #pragma unroll
    for (int i = 0; i < 8; ++i) {
        const int row = w * 8 + i;
        gload_lds16(gx4 + row * 64 + lane, &xs4[row][0]);
    }
#else
    {
        const int p = t >> 3, q = t & 7;
        #pragma unroll
        for (int j = 0; j < 8; ++j)
            xs4[p][q + 8 * j] = gx4[p * 64 + q + 8 * j];
    }
#endif
    {
        const int k = t >> 3, seg = t & 7;   // thread covers cw[k][seg*32 .. +31]
        const float4* cw4 = (const float4*)cw;
        float s = 0.f;
        #pragma unroll
        for (int jj = 0; jj < 4; ++jj) {
            float4 u0 = cw4[k * 64 + seg * 8 + 2 * jj];
            float4 u1 = cw4[k * 64 + seg * 8 + 2 * jj + 1];
            s += u0.x * u0.x + u0.y * u0.y + u0.z * u0.z + u0.w * u0.w
               + u1.x * u1.x + u1.y * u1.y + u1.z * u1.z + u1.w * u1.w;
            *(short8*)&u.p0.cwbf[k][seg * 32 + 8 * jj] = pack8(u0, u1);
        }
        u.p0.ccred[seg][k] = s;
    }
    if (t < 32) sf_lds[t] = sf[t];
    __syncthreads();

    // ---- phase 1: GEMM1 dot = x.cw^T (both operands LDS); materialize xbf ---
    const int mt = w >> 1, half = w & 1;
    const int lrow = lane & 15;
    const int g = lane >> 4;
    const float* xsf = (const float*)xs4;

    f32x4 D0 = {0.f, 0.f, 0.f, 0.f}, D1 = {0.f, 0.f, 0.f, 0.f};
    float xxp = 0.f;
    #pragma unroll
    for (int ks = 0; ks < 4; ++ks) {
        const int ch = half * 128 + ks * 32 + g * 8;
        const int row = mt * 16 + lrow;
        const float* ap = xsf + row * 260 + ch;
        float4 uu = *(const float4*)ap;
        float4 vv = *(const float4*)(ap + 4);
        xxp += uu.x * uu.x + uu.y * uu.y + uu.z * uu.z + uu.w * uu.w
             + vv.x * vv.x + vv.y * vv.y + vv.z * vv.z + vv.w * vv.w;
        short8 a = pack8(uu, vv);
        *(short8*)&xbf[row][ch] = a;
        short8 b0 = *(const short8*)&u.p0.cwbf[lrow][ch];
        short8 b1 = *(const short8*)&u.p0.cwbf[16 + lrow][ch];
        D0 = __builtin_amdgcn_mfma_f32_16x16x32_bf16(a, b0, D0, 0, 0, 0);
        D1 = __builtin_amdgcn_mfma_f32_16x16x32_bf16(a, b1, D1, 0, 0, 0);
    }
    xxp += __shfl_xor(xxp, 16, 64);
    xxp += __shfl_xor(xxp, 32, 64);
    if (t < 32) {
        float s = 0.f;
        #pragma unroll
        for (int j = 0; j < 8; ++j) s += u.p0.ccred[j][t];
        cc_lds[t] = s;
    }
    __syncthreads();                         // p0 reads done; repurpose as p1

    if (lane < 16) u.p1.xxr[mt][half][lane] = xxp;
    u.p1.dred[mt][half][0][lane] = make_float4(D0[0], D0[1], D0[2], D0[3]);
    u.p1.dred[mt][half][1][lane] = make_float4(D1[0], D1[1], D1[2], D1[3]);
    __syncthreads();

    // ---- phase 2: softmax over k; write w_lds fp32 + wT bf16 ----
    {
        float4 a0 = u.p1.dred[mt][0][0][lane], b0 = u.p1.dred[mt][1][0][lane];
        float4 a1 = u.p1.dred[mt][0][1][lane], b1 = u.p1.dred[mt][1][1][lane];
        float d0[4] = {a0.x + b0.x, a0.y + b0.y, a0.z + b0.z, a0.w + b0.w};
        float d1[4] = {a1.x + b1.x, a1.y + b1.y, a1.z + b1.z, a1.w + b1.w};
        const int k0 = lane & 15, k1 = 16 + k0;
        const float sf0 = sf_lds[k0], sf1 = sf_lds[k1];
        const float cc0 = cc_lds[k0], cc1 = cc_lds[k1];
        #pragma unroll
        for (int r = 0; r < 4; ++r) {
            const int pl = (lane >> 4) * 4 + r;
            const float xxv = u.p1.xxr[mt][0][pl] + u.p1.xxr[mt][1][pl];
            float s0 = sf0 * (xxv - 2.f * d0[r] + cc0);
            float s1 = sf1 * (xxv - 2.f * d1[r] + cc1);
            float m = fmaxf(s0, s1);
            #pragma unroll
            for (int msk = 1; msk <= 8; msk <<= 1) m = fmaxf(m, __shfl_xor(m, msk, 64));
            float e0 = __expf(s0 - m), e1 = __expf(s1 - m);
            float sm = e0 + e1;
            #pragma unroll
            for (int msk = 1; msk <= 8; msk <<= 1) sm += __shfl_xor(sm, msk, 64);
            const float inv = 1.f / sm;
            if (half == 0) {
                const int n = mt * 16 + pl;
                const float w0 = e0 * inv, w1 = e1 * inv;
                w_lds[n][k0] = w0;
                w_lds[n][k1] = w1;
                wT[k0][n] = f2bf(w0);
                wT[k1][n] = f2bf(w1);
            }
        }
    }
    __syncthreads();

    // ---- phase 3: GEMM2 S1 = w^T . x ; write pS1 + pW ----
    {
        short8 a0 = *(const short8*)&wT[lrow][8 * g];
        short8 a1 = *(const short8*)&wT[16 + lrow][8 * g];
        f32x4 E00 = {0,0,0,0}, E01 = {0,0,0,0}, E02 = {0,0,0,0}, E03 = {0,0,0,0};
        f32x4 E10 = {0,0,0,0}, E11 = {0,0,0,0}, E12 = {0,0,0,0}, E13 = {0,0,0,0};
        const int cbase = w * 64;
        const unsigned short* xbu = &xbf[0][0];
        #pragma unroll
        for (int nt = 0; nt < 4; ++nt) {
            const int c = cbase + nt * 16 + lrow;
            short8 bf;
            #pragma unroll
            for (int e = 0; e < 8; ++e)
                bf[e] = (short)xbu[(8 * g + e) * 264 + c];
            if (nt == 0) { E00 = __builtin_amdgcn_mfma_f32_16x16x32_bf16(a0, bf, E00, 0,0,0);
                           E10 = __builtin_amdgcn_mfma_f32_16x16x32_bf16(a1, bf, E10, 0,0,0); }
            if (nt == 1) { E01 = __builtin_amdgcn_mfma_f32_16x16x32_bf16(a0, bf, E01, 0,0,0);
                           E11 = __builtin_amdgcn_mfma_f32_16x16x32_bf16(a1, bf, E11, 0,0,0); }
            if (nt == 2) { E02 = __builtin_amdgcn_mfma_f32_16x16x32_bf16(a0, bf, E02, 0,0,0);
                           E12 = __builtin_amdgcn_mfma_f32_16x16x32_bf16(a1, bf, E12, 0,0,0); }
            if (nt == 3) { E03 = __builtin_amdgcn_mfma_f32_16x16x32_bf16(a0, bf, E03, 0,0,0);
                           E13 = __builtin_amdgcn_mfma_f32_16x16x32_bf16(a1, bf, E13, 0,0,0); }
        }
        float* dst = pS1 + (size_t)bid * 8192;
        const int krow = 4 * g;
        #pragma unroll
        for (int reg = 0; reg < 4; ++reg) {
            const int k0r = (krow + reg) * 256;
            const int k1r = (16 + krow + reg) * 256;
            dst[k0r + cbase +  0 + lrow] = E00[reg];
            dst[k0r + cbase + 16 + lrow] = E01[reg];
            dst[k0r + cbase + 32 + lrow] = E02[reg];
            dst[k0r + cbase + 48 + lrow] = E03[reg];
            dst[k1r + cbase +  0 + lrow] = E10[reg];
            dst[k1r + cbase + 16 + lrow] = E11[reg];
            dst[k1r + cbase + 32 + lrow] = E12[reg];
            dst[k1r + cbase + 48 + lrow] = E13[reg];
        }
    }
    if (t < 32) {
        float s = 0.f;
        #pragma unroll
        for (int p = 0; p < 32; ++p) s += w_lds[p][t];
        pW[bid * 32 + t] = s;
    }
}

// -------- reduce partials -> enc rows (512 blocks, one (b,k) row each) -------
__global__ __launch_bounds__(256) void enc_reduce(
    const float* __restrict__ pS1, const float* __restrict__ pW,
    const float* __restrict__ cw, float* __restrict__ enc)
{
    const int row = blockIdx.x;        // b*32 + k
    const int b = row >> 5;
    const int k = row & 31;
    const int c = threadIdx.x;
    float s = 0.f;
    #pragma unroll
    for (int jj = 0; jj < 32; ++jj)
        s += pS1[(size_t)(b * 32 + jj) * 8192 + k * 256 + c];
    // wsum: one lane-strided gather + butterfly within 32-lane halves
    const int lane = c & 63;
    float wp = pW[(b * 32 + (lane & 31)) * 32 + k];
    #pragma unroll
    for (int m = 1; m <= 16; m <<= 1) wp += __shfl_xor(wp, m, 64);
    enc[row * 256 + c] = s - wp * cw[k * 256 + c];
}

// -------- per-channel partial stats over 16 rows each (32 blocks) ------------
__global__ __launch_bounds__(256) void enc_stats2(
    const float* __restrict__ enc, float* __restrict__ pst)
{
    const int p = blockIdx.x;
    const int c = threadIdx.x;
    float s = 0.f, ss = 0.f;
    #pragma unroll
    for (int r = 0; r < 16; ++r) {
        float v = enc[(p * 16 + r) * 256 + c];
        s += v;
        ss = fmaf(v, v, ss);
    }
    pst[p * 512 + c] = s;
    pst[p * 512 + 256 + c] = ss;
}

// -------- BN finalize + ReLU + sum over k (16 blocks) ------------------------
__global__ __launch_bounds__(256) void enc_out(
    const float* __restrict__ enc, const float* __restrict__ pst,
    const float* __restrict__ gamma, const float* __restrict__ beta,
    float* __restrict__ out)
{
    const int b = blockIdx.x;
    const int c = threadIdx.x;
    float S = 0.f, SS = 0.f;
    #pragma unroll
    for (int p = 0; p < 32; ++p) {
        S  += pst[p * 512 + c];
        SS += pst[p * 512 + 256 + c];
    }
    const float mean = S * (1.f / 512.f);
    const float var = SS * (1.f / 512.f) - mean * mean;
    const float g = gamma[c] * rsqrtf(var + BN_EPS);
    const float bt = beta[c];
    float o = 0.f;
    #pragma unroll
    for (int k = 0; k < 32; ++k) {
        float e = enc[(b * 32 + k) * 256 + c];
        float v = (e - mean) * g + bt;
        o += fmaxf(v, 0.f);
    }
    out[b * 256 + c] = o;
}

extern "C" void kernel_launch(void* const* d_in, const int* in_sizes, int n_in,
                              void* d_out, int out_size, void* d_ws, size_t ws_size,
                              hipStream_t stream) {
    const float* x     = (const float*)d_in[0];
    const float* cw    = (const float*)d_in[1];
    const float* sf    = (const float*)d_in[2];
    const float* gamma = (const float*)d_in[3];
    const float* beta  = (const float*)d_in[4];
    float* out = (float*)d_out;
    float* ws  = (float*)d_ws;

    float* pS1 = ws;                               // 512*8192
    float* pW  = pS1 + (size_t)512 * 8192;         // 512*32
    float* enc = pW + (size_t)512 * 32;            // 512*256
    float* pst = enc + (size_t)512 * 256;          // 32*512

    enc_main_mfma<<<512, 256, 0, stream>>>(x, cw, sf, pS1, pW);
    enc_reduce<<<512, 256, 0, stream>>>(pS1, pW, cw, enc);
    enc_stats2<<<32, 256, 0, stream>>>(enc, pst);
    enc_out<<<16, 256, 0, stream>>>(enc, pst, gamma, beta, out);
}

// Round 6
// 26.657 us; speedup vs baseline: 1.5537x; 1.0894x over previous
//
#include <hip/hip_runtime.h>
#include <hip/hip_bf16.h>

// Encoder: B=16, n=1024, C=256, K=32, fp32 in/out.
// GEMM1 (MFMA): dot[n,k] = x.cw^T ; sqnorm = xx - 2 dot + cc (fp32 softmax args)
// w = softmax_k(sf*sqnorm)
// GEMM2 (MFMA): S1[k,c] = sum_n w[n,k] x[n,c]  (bf16 in, fp32 accum, regs persist
//               across 2 position-tiles per block -> partials halved)
// enc = S1 - wsum*cw;  out[b,c] = sum_k relu((enc-mean)*rsqrt(var+eps)*gamma+beta)

#define BN_EPS 1e-3f

typedef __attribute__((ext_vector_type(8))) short short8;
typedef __attribute__((ext_vector_type(4))) float f32x4;

static __device__ inline unsigned short f2bf(float f) {
    unsigned int u = __float_as_uint(f);
    unsigned int r = (u + 0x7fffu + ((u >> 16) & 1u)) >> 16;
    return (unsigned short)r;
}

static __device__ inline short8 pack8(float4 u, float4 v) {
    short8 r;
    r[0] = (short)f2bf(u.x); r[1] = (short)f2bf(u.y);
    r[2] = (short)f2bf(u.z); r[3] = (short)f2bf(u.w);
    r[4] = (short)f2bf(v.x); r[5] = (short)f2bf(v.y);
    r[6] = (short)f2bf(v.z); r[7] = (short)f2bf(v.w);
    return r;
}

#if __has_builtin(__builtin_amdgcn_global_load_lds)
#define HAVE_GLOAD_LDS 1
typedef const __attribute__((address_space(1))) void* as1_cvp;
typedef __attribute__((address_space(3))) void* as3_vp;
static __device__ inline void gload_lds16(const void* g, void* s) {
    __builtin_amdgcn_global_load_lds((as1_cvp)g, (as3_vp)s, 16, 0, 0);
}
#else
#define HAVE_GLOAD_LDS 0
#endif

// ------------- MFMA main kernel: 256 blocks x 512 thr, 2 tiles/block ---------
__global__ __launch_bounds__(512, 1) void enc_main_mfma(
    const float* __restrict__ x, const float* __restrict__ cw,
    const float* __restrict__ sf, float* __restrict__ pS1, float* __restrict__ pW)
{
    const int bid = blockIdx.x;          // 256 blocks
    const int b   = bid >> 4;            // batch
    const int jb2 = bid & 15;            // 64-position super-tile
    const int t = threadIdx.x;
    const int w = t >> 6;                // 8 waves
    const int lane = t & 63;
    const int mt   = w >> 2;             // M-tile (16 rows)
    const int half = (w >> 1) & 1;       // channel half (128)
    const int dup  = w & 1;              // ks-half (2 of 4 k-slices)
    const int lrow = lane & 15;
    const int g    = lane >> 4;

    __shared__ float4 xs4[32][65];             // x tile fp32 (reused tile1)
    __shared__ unsigned short cwbf[32][264];   // cw bf16 (block-lifetime)
    __shared__ float  ccred[16][32];
    __shared__ float4 dred[2][2][2][2][64];    // [mt][half][dup][nt][lane]
    __shared__ float  xxr[2][2][2][16];        // [mt][half][dup][pos]
    __shared__ unsigned short xbf[32][264];    // x bf16 (per tile)
    __shared__ unsigned short wT[32][40];      // w^T bf16 (per tile)
    __shared__ float  w_lds[2][32][33];        // fp32 w per tile (wsum)
    __shared__ float  cc_lds[32];
    __shared__ float  sf_lds[32];

    const float4* gx4 = (const float4*)(x + (size_t)b * 1024 * 256)
                        + (size_t)jb2 * 64 * 64;

    // ---- phase 0: DMA tile0 -> xs4; pack cw->bf16 + cc partials; sf ----
#if HAVE_GLOAD_LDS
    #pragma unroll
    for (int i = 0; i < 4; ++i) {
        const int row = w * 4 + i;
        gload_lds16(gx4 + row * 64 + lane, &xs4[row][0]);
    }
#else
    {
        const int p = t >> 4, q = t & 15;
        #pragma unroll
        for (int j = 0; j < 4; ++j)
            xs4[p][q + 16 * j] = gx4[p * 64 + q + 16 * j];
    }
#endif
    {
        const int k = t >> 4, seg = t & 15;  // 16 channels per thread
        const float4* cw4 = (const float4*)cw;
        float s = 0.f;
        #pragma unroll
        for (int jj = 0; jj < 2; ++jj) {
            float4 u0 = cw4[k * 64 + seg * 4 + 2 * jj];
            float4 u1 = cw4[k * 64 + seg * 4 + 2 * jj + 1];
            s += u0.x * u0.x + u0.y * u0.y + u0.z * u0.z + u0.w * u0.w
               + u1.x * u1.x + u1.y * u1.y + u1.z * u1.z + u1.w * u1.w;
            *(short8*)&cwbf[k][seg * 16 + 8 * jj] = pack8(u0, u1);
        }
        ccred[seg][k] = s;
    }
    if (t < 32) sf_lds[t] = sf[t];
    __syncthreads();

    if (t < 32) {                        // overlaps GEMM1; read post-bar1
        float s = 0.f;
        #pragma unroll
        for (int j = 0; j < 16; ++j) s += ccred[j][t];
        cc_lds[t] = s;
    }

    f32x4 E00 = {0,0,0,0}, E01 = {0,0,0,0}, E10 = {0,0,0,0}, E11 = {0,0,0,0};
    const float* xsf = (const float*)xs4;

    #pragma unroll
    for (int tile = 0; tile < 2; ++tile) {
        // ---- GEMM1: dot = x.cw^T (this wave: 2 of 4 k-slices); write xbf ----
        f32x4 D0 = {0,0,0,0}, D1 = {0,0,0,0};
        float xxp = 0.f;
        #pragma unroll
        for (int k2 = 0; k2 < 2; ++k2) {
            const int ks = dup * 2 + k2;
            const int ch = half * 128 + ks * 32 + g * 8;
            const int row = mt * 16 + lrow;
            const float* ap = xsf + row * 260 + ch;
            float4 uu = *(const float4*)ap;
            float4 vv = *(const float4*)(ap + 4);
            xxp += uu.x * uu.x + uu.y * uu.y + uu.z * uu.z + uu.w * uu.w
                 + vv.x * vv.x + vv.y * vv.y + vv.z * vv.z + vv.w * vv.w;
            short8 a = pack8(uu, vv);
            *(short8*)&xbf[row][ch] = a;
            short8 b0 = *(const short8*)&cwbf[lrow][ch];
            short8 b1 = *(const short8*)&cwbf[16 + lrow][ch];
            D0 = __builtin_amdgcn_mfma_f32_16x16x32_bf16(a, b0, D0, 0, 0, 0);
            D1 = __builtin_amdgcn_mfma_f32_16x16x32_bf16(a, b1, D1, 0, 0, 0);
        }
        xxp += __shfl_xor(xxp, 16, 64);
        xxp += __shfl_xor(xxp, 32, 64);
        if (lane < 16) xxr[mt][half][dup][lane] = xxp;
        dred[mt][half][dup][0][lane] = make_float4(D0[0], D0[1], D0[2], D0[3]);
        dred[mt][half][dup][1][lane] = make_float4(D1[0], D1[1], D1[2], D1[3]);
        __syncthreads();                               // bar1

        if (tile == 0) {
            // prefetch tile1 into xs4; stays in flight across raw bar2
#if HAVE_GLOAD_LDS
            #pragma unroll
            for (int i = 0; i < 4; ++i) {
                const int row = w * 4 + i;
                gload_lds16(gx4 + (32 + row) * 64 + lane, &xs4[row][0]);
            }
#else
            const int p = t >> 4, q = t & 15;
            #pragma unroll
            for (int j = 0; j < 4; ++j)
                xs4[p][q + 16 * j] = gx4[(32 + p) * 64 + q + 16 * j];
#endif
        }

        // ---- softmax over k (all waves compute; (half,dup)==(0,0) writes) ---
        {
            const int k0 = lrow, k1 = 16 + lrow;
            float d0[4], d1[4];
            #pragma unroll
            for (int nt = 0; nt < 2; ++nt) {
                float4 s00 = dred[mt][0][0][nt][lane];
                float4 s01 = dred[mt][0][1][nt][lane];
                float4 s10 = dred[mt][1][0][nt][lane];
                float4 s11 = dred[mt][1][1][nt][lane];
                float* dd = nt ? d1 : d0;
                dd[0] = s00.x + s01.x + s10.x + s11.x;
                dd[1] = s00.y + s01.y + s10.y + s11.y;
                dd[2] = s00.z + s01.z + s10.z + s11.z;
                dd[3] = s00.w + s01.w + s10.w + s11.w;
            }
            const float sf0 = sf_lds[k0], sf1 = sf_lds[k1];
            const float cc0 = cc_lds[k0], cc1 = cc_lds[k1];
            #pragma unroll
            for (int r = 0; r < 4; ++r) {
                const int pl = g * 4 + r;
                const float xxv = xxr[mt][0][0][pl] + xxr[mt][0][1][pl]
                                + xxr[mt][1][0][pl] + xxr[mt][1][1][pl];
                float s0 = sf0 * (xxv - 2.f * d0[r] + cc0);
                float s1 = sf1 * (xxv - 2.f * d1[r] + cc1);
                float m = fmaxf(s0, s1);
                #pragma unroll
                for (int msk = 1; msk <= 8; msk <<= 1) m = fmaxf(m, __shfl_xor(m, msk, 64));
                float e0 = __expf(s0 - m), e1 = __expf(s1 - m);
                float sm = e0 + e1;
                #pragma unroll
                for (int msk = 1; msk <= 8; msk <<= 1) sm += __shfl_xor(sm, msk, 64);
                const float inv = 1.f / sm;
                if (half == 0 && dup == 0) {
                    const int n = mt * 16 + pl;
                    const float w0v = e0 * inv, w1v = e1 * inv;
                    w_lds[tile][n][k0] = w0v;
                    w_lds[tile][n][k1] = w1v;
                    wT[k0][n] = f2bf(w0v);
                    wT[k1][n] = f2bf(w1v);
                }
            }
        }
        // bar2: execution + LDS drain only; DMA (vmcnt) stays in flight
        asm volatile("s_waitcnt lgkmcnt(0)" ::: "memory");
        __builtin_amdgcn_sched_barrier(0);
        __builtin_amdgcn_s_barrier();
        __builtin_amdgcn_sched_barrier(0);

        // ---- GEMM2: accumulate S1 fragments across tiles ----
        {
            short8 a0 = *(const short8*)&wT[lrow][8 * g];
            short8 a1 = *(const short8*)&wT[16 + lrow][8 * g];
            const unsigned short* xbu = &xbf[0][0];
            #pragma unroll
            for (int nt = 0; nt < 2; ++nt) {
                const int c = w * 32 + nt * 16 + lrow;
                short8 bf;
                #pragma unroll
                for (int e = 0; e < 8; ++e)
                    bf[e] = (short)xbu[(8 * g + e) * 264 + c];
                if (nt == 0) {
                    E00 = __builtin_amdgcn_mfma_f32_16x16x32_bf16(a0, bf, E00, 0, 0, 0);
                    E10 = __builtin_amdgcn_mfma_f32_16x16x32_bf16(a1, bf, E10, 0, 0, 0);
                } else {
                    E01 = __builtin_amdgcn_mfma_f32_16x16x32_bf16(a0, bf, E01, 0, 0, 0);
                    E11 = __builtin_amdgcn_mfma_f32_16x16x32_bf16(a1, bf, E11, 0, 0, 0);
                }
            }
        }
        if (tile == 0) __syncthreads();    // bar3: drains DMA; xbf/wT reusable
    }

    // ---- stores: one 32x256 partial per block ----
    float* dst = pS1 + (size_t)bid * 8192;
    #pragma unroll
    for (int reg = 0; reg < 4; ++reg) {
        const int k0r = (4 * g + reg) * 256;
        const int k1r = (16 + 4 * g + reg) * 256;
        dst[k0r + w * 32 +  0 + lrow] = E00[reg];
        dst[k0r + w * 32 + 16 + lrow] = E01[reg];
        dst[k1r + w * 32 +  0 + lrow] = E10[reg];
        dst[k1r + w * 32 + 16 + lrow] = E11[reg];
    }
    if (t < 32) {
        float s = 0.f;
        #pragma unroll
        for (int p = 0; p < 32; ++p) s += w_lds[0][p][t] + w_lds[1][p][t];
        pW[bid * 32 + t] = s;
    }
}

// -------- reduce partials -> enc rows (512 blocks, one (b,k) row each) -------
__global__ __launch_bounds__(256) void enc_reduce(
    const float* __restrict__ pS1, const float* __restrict__ pW,
    const float* __restrict__ cw, float* __restrict__ enc)
{
    const int row = blockIdx.x;        // b*32 + k
    const int b = row >> 5;
    const int k = row & 31;
    const int c = threadIdx.x;
    float s = 0.f;
    #pragma unroll
    for (int jj = 0; jj < 16; ++jj)
        s += pS1[(size_t)(b * 16 + jj) * 8192 + k * 256 + c];
    const int lane = c & 63;
    float wp = pW[(b * 16 + (lane & 15)) * 32 + k];
    #pragma unroll
    for (int m = 1; m <= 8; m <<= 1) wp += __shfl_xor(wp, m, 64);
    enc[row * 256 + c] = s - wp * cw[k * 256 + c];
}

// -------- per-channel partial stats over 8 rows each (64 blocks) -------------
__global__ __launch_bounds__(256) void enc_stats2(
    const float* __restrict__ enc, float* __restrict__ pst)
{
    const int p = blockIdx.x;
    const int c = threadIdx.x;
    float s = 0.f, ss = 0.f;
    #pragma unroll
    for (int r = 0; r < 8; ++r) {
        float v = enc[(p * 8 + r) * 256 + c];
        s += v;
        ss = fmaf(v, v, ss);
    }
    pst[p * 512 + c] = s;
    pst[p * 512 + 256 + c] = ss;
}

// -------- BN finalize + ReLU + sum over k (16 blocks) ------------------------
__global__ __launch_bounds__(256) void enc_out(
    const float* __restrict__ enc, const float* __restrict__ pst,
    const float* __restrict__ gamma, const float* __restrict__ beta,
    float* __restrict__ out)
{
    const int b = blockIdx.x;
    const int c = threadIdx.x;
    float S = 0.f, SS = 0.f;
    #pragma unroll 8
    for (int p = 0; p < 64; ++p) {
        S  += pst[p * 512 + c];
        SS += pst[p * 512 + 256 + c];
    }
    const float mean = S * (1.f / 512.f);
    const float var = SS * (1.f / 512.f) - mean * mean;
    const float g = gamma[c] * rsqrtf(var + BN_EPS);
    const float bt = beta[c];
    float o = 0.f;
    #pragma unroll
    for (int k = 0; k < 32; ++k) {
        float e = enc[(b * 32 + k) * 256 + c];
        float v = (e - mean) * g + bt;
        o += fmaxf(v, 0.f);
    }
    out[b * 256 + c] = o;
}

extern "C" void kernel_launch(void* const* d_in, const int* in_sizes, int n_in,
                              void* d_out, int out_size, void* d_ws, size_t ws_size,
                              hipStream_t stream) {
    const float* x     = (const float*)d_in[0];
    const float* cw    = (const float*)d_in[1];
    const float* sf    = (const float*)d_in[2];
    const float* gamma = (const float*)d_in[3];
    const float* beta  = (const float*)d_in[4];
    float* out = (float*)d_out;
    float* ws  = (float*)d_ws;

    float* pS1 = ws;                               // 256*8192
    float* pW  = pS1 + (size_t)256 * 8192;         // 256*32
    float* enc = pW + (size_t)256 * 32;            // 512*256
    float* pst = enc + (size_t)512 * 256;          // 64*512

    enc_main_mfma<<<256, 512, 0, stream>>>(x, cw, sf, pS1, pW);
    enc_reduce<<<512, 256, 0, stream>>>(pS1, pW, cw, enc);
    enc_stats2<<<64, 256, 0, stream>>>(enc, pst);
    enc_out<<<16, 256, 0, stream>>>(enc, pst, gamma, beta, out);
}